// Round 5
// baseline (800.137 us; speedup 1.0000x reference)
//
#include <hip/hip_runtime.h>

typedef unsigned short u16;
typedef unsigned int u32;
typedef __attribute__((ext_vector_type(8))) short short8;
typedef __attribute__((ext_vector_type(4))) float f32x4;

#define M_ROWS 32768

__device__ __forceinline__ float bf2f(u16 u) {
  u32 x = ((u32)u) << 16;
  return __builtin_bit_cast(float, x);
}
__device__ __forceinline__ u16 f2bf(float f) {
  u32 x = __builtin_bit_cast(u32, f);
  x += 0x7fffu + ((x >> 16) & 1u);
  return (u16)(x >> 16);
}
// load 8 fp32 from p, RNE-round to one short8
__device__ __forceinline__ short8 ld8f(const float* p) {
  f32x4 x0 = *(const f32x4*)p;
  f32x4 x1 = *(const f32x4*)(p + 4);
  short8 s;
#pragma unroll
  for (int i = 0; i < 4; ++i) { s[i] = (short)f2bf(x0[i]); s[4 + i] = (short)f2bf(x1[i]); }
  return s;
}

// ---------------- generic 128x128 GEMM (G1: wbond w/ rank-4 tail, G2: rbond) ----
struct SegF { const void* ptr; int ld; int kstart; int dt; }; // dt: 0=fp32, 1=bf16
struct GArgs {
  SegF seg[2];
  int nseg;
  const u16* bt;       // B^T [N][K] bf16 (from prep)
  const float* biasf;  // [N] fp32
  u16* out;            // [M][N] relu'd bf16 (workspace intermediate)
  int K;
  int N;
  const float* tail_w; // fp32 wbond_w rows 512..515 (ld 512) or null
  const float* tail_x; // fp32 bond_onehot [M][4] or null
};

__global__ __launch_bounds__(256) void gemm_ms(GArgs a) {
  __shared__ u16 lds[8192]; // As[128][32] @0, Bs[128][32] @4096
  const int tid = threadIdx.x;
  const int bm = blockIdx.x, bn = blockIdx.y;
  const int wave = tid >> 6, lane = tid & 63;
  const int wm = wave >> 1, wn = wave & 1;
  const int lm = lane & 15, lq = lane >> 4;
  const int rA = tid >> 2, kq = (tid & 3) * 8;
  const int gm0 = bm * 128 + rA, gm1 = gm0 + 64;
  const int gn0 = bn * 128 + rA, gn1 = gn0 + 64;

  u16* As = lds;
  u16* Bs = lds + 4096;
  u16* la0 = As + tid * 8;
  u16* la1 = As + 2048 + tid * 8;
  u16* lb0 = Bs + tid * 8;
  u16* lb1 = Bs + 2048 + tid * 8;

  f32x4 acc[4][4] = {};
  const int K = a.K;
  for (int kb = 0; kb < K; kb += 32) {
    const SegF* s = &a.seg[0];
    if (a.nseg > 1 && kb >= a.seg[1].kstart) s = &a.seg[1];
    const int krel = kb - s->kstart + kq;
    *(short8*)lb0 = *(const short8*)(a.bt + (size_t)gn0 * K + kb + kq);
    *(short8*)lb1 = *(const short8*)(a.bt + (size_t)gn1 * K + kb + kq);
    if (s->dt == 0) {
      const float* p = (const float*)s->ptr;
      *(short8*)la0 = ld8f(p + (size_t)gm0 * s->ld + krel);
      *(short8*)la1 = ld8f(p + (size_t)gm1 * s->ld + krel);
    } else {
      const u16* p = (const u16*)s->ptr;
      *(short8*)la0 = *(const short8*)(p + (size_t)gm0 * s->ld + krel);
      *(short8*)la1 = *(const short8*)(p + (size_t)gm1 * s->ld + krel);
    }
    __syncthreads();

    short8 af[4], bfr[4];
#pragma unroll
    for (int i = 0; i < 4; ++i)
      af[i] = *(const short8*)&As[(wm * 64 + i * 16 + lm) * 32 + lq * 8];
#pragma unroll
    for (int j = 0; j < 4; ++j)
      bfr[j] = *(const short8*)&Bs[(wn * 64 + j * 16 + lm) * 32 + lq * 8];
#pragma unroll
    for (int i = 0; i < 4; ++i)
#pragma unroll
      for (int j = 0; j < 4; ++j)
        acc[i][j] = __builtin_amdgcn_mfma_f32_16x16x32_bf16(af[i], bfr[j], acc[i][j], 0, 0, 0);
    __syncthreads();
  }

  const int gc0 = bn * 128 + wn * 64 + lm;
  float biasv[4], tw[4][4];
#pragma unroll
  for (int j = 0; j < 4; ++j) {
    const int gc = gc0 + j * 16;
    biasv[j] = a.biasf[gc];
    if (a.tail_w) {
#pragma unroll
      for (int k = 0; k < 4; ++k) tw[j][k] = a.tail_w[k * 512 + gc];
    }
  }
#pragma unroll
  for (int i = 0; i < 4; ++i) {
#pragma unroll
    for (int r = 0; r < 4; ++r) {
      const int gr = bm * 128 + wm * 64 + i * 16 + lq * 4 + r;
      float tx0 = 0.f, tx1 = 0.f, tx2 = 0.f, tx3 = 0.f;
      if (a.tail_w) {
        tx0 = a.tail_x[gr * 4 + 0];
        tx1 = a.tail_x[gr * 4 + 1];
        tx2 = a.tail_x[gr * 4 + 2];
        tx3 = a.tail_x[gr * 4 + 3];
      }
#pragma unroll
      for (int j = 0; j < 4; ++j) {
        float v = acc[i][j][r] + biasv[j];
        if (a.tail_w) v += tx0 * tw[j][0] + tx1 * tw[j][1] + tx2 * tw[j][2] + tx3 * tw[j][3];
        v = v > 0.f ? v : 0.f;
        a.out[(size_t)gr * a.N + gc0 + j * 16] = f2bf(v);
      }
    }
  }
}

// ---------------- topo+atom: layer1 GEMM (K=1152) with fused layer-2 heads ------
struct TAArgs {
  const float* gvec; const float* xnode; const float* src; const int* bidx;
  const u16* bt;      // TAT [1024][1152] bf16
  const float* tb1;   // topo_b1 [512] fp32
  const float* ab1;   // atom_b1 [512] fp32
  const float* tw2;   // topo_w2 [512] fp32
  const float* tb2;   // topo_b2 [1] fp32
  const u16* aw2t;    // AT2 [64][512] bf16
  const float* ab2;   // atom_b2 [64] fp32
  float* out;         // d_out fp32 [M][69]
};

__global__ __launch_bounds__(256) void gemm_ta_heads(TAArgs a) {
  __shared__ u16 lds[8192];
  __shared__ u16 hbuf[128 * 136];
  const int tid = threadIdx.x;
  const int bm = blockIdx.x, half = blockIdx.y; // 0=topo cols, 1=atom cols
  const int wave = tid >> 6, lane = tid & 63;
  const int wm = wave >> 1, wn = wave & 1;
  const int lm = lane & 15, lq = lane >> 4;
  const int rA = tid >> 2, kq = (tid & 3) * 8;
  const int gm0 = bm * 128 + rA, gm1 = gm0 + 64;
  const int b0 = a.bidx[gm0], b1 = a.bidx[gm1];

  u16* As = lds;
  u16* Bs = lds + 4096;
  u16* la0 = As + tid * 8;
  u16* la1 = As + 2048 + tid * 8;
  u16* lb0 = Bs + tid * 8;
  u16* lb1 = Bs + 2048 + tid * 8;

  float topo_acc = 0.f;
  f32x4 acc2[2][4] = {};

  for (int t = 0; t < 4; ++t) {
    const int colbase = half * 512 + t * 128;
    f32x4 acc[4][4] = {};
    for (int kb = 0; kb < 1152; kb += 32) {
      *(short8*)lb0 = *(const short8*)(a.bt + (size_t)(colbase + rA) * 1152 + kb + kq);
      *(short8*)lb1 = *(const short8*)(a.bt + (size_t)(colbase + 64 + rA) * 1152 + kb + kq);
      const float* p; int ks, ld, r0 = gm0, r1 = gm1;
      if (kb < 512)       { p = a.gvec;  ks = 0;    ld = 512; }
      else if (kb < 1024) { p = a.xnode; ks = 512;  ld = 512; }
      else                { p = a.src;   ks = 1024; ld = 128; r0 = b0; r1 = b1; }
      const int krel = kb - ks + kq;
      *(short8*)la0 = ld8f(p + (size_t)r0 * ld + krel);
      *(short8*)la1 = ld8f(p + (size_t)r1 * ld + krel);
      __syncthreads();
      short8 af[4], bfr[4];
#pragma unroll
      for (int i = 0; i < 4; ++i)
        af[i] = *(const short8*)&As[(wm * 64 + i * 16 + lm) * 32 + lq * 8];
#pragma unroll
      for (int j = 0; j < 4; ++j)
        bfr[j] = *(const short8*)&Bs[(wn * 64 + j * 16 + lm) * 32 + lq * 8];
#pragma unroll
      for (int i = 0; i < 4; ++i)
#pragma unroll
        for (int j = 0; j < 4; ++j)
          acc[i][j] = __builtin_amdgcn_mfma_f32_16x16x32_bf16(af[i], bfr[j], acc[i][j], 0, 0, 0);
      __syncthreads();
    }
    // h = relu(acc + b1) -> hbuf
    const float* bsrc = half ? a.ab1 : a.tb1;
    const int c0 = wn * 64 + lm;
    float bv[4];
#pragma unroll
    for (int j = 0; j < 4; ++j) bv[j] = bsrc[t * 128 + c0 + j * 16];
#pragma unroll
    for (int i = 0; i < 4; ++i) {
#pragma unroll
      for (int r = 0; r < 4; ++r) {
        const int rl = wm * 64 + i * 16 + lq * 4 + r;
#pragma unroll
        for (int j = 0; j < 4; ++j) {
          float v = acc[i][j][r] + bv[j];
          v = v > 0.f ? v : 0.f;
          hbuf[rl * 136 + c0 + j * 16] = f2bf(v);
        }
      }
    }
    __syncthreads();

    if (half == 0) {
      const int srow = tid >> 1, sh = tid & 1;
      const u16* hrow = &hbuf[srow * 136 + sh * 64];
      float s = 0.f;
      for (int cc = 0; cc < 64; ++cc)
        s += bf2f(hrow[cc]) * a.tw2[t * 128 + sh * 64 + cc];
      topo_acc += s;
    } else {
#pragma unroll
      for (int ks2 = 0; ks2 < 4; ++ks2) {
#pragma unroll
        for (int i2 = 0; i2 < 2; ++i2) {
          const short8 af2 = *(const short8*)&hbuf[(wave * 32 + i2 * 16 + lm) * 136 + ks2 * 32 + lq * 8];
#pragma unroll
          for (int j2 = 0; j2 < 4; ++j2) {
            const short8 bf2v = *(const short8*)&a.aw2t[(size_t)(j2 * 16 + lm) * 512 + t * 128 + ks2 * 32 + lq * 8];
            acc2[i2][j2] = __builtin_amdgcn_mfma_f32_16x16x32_bf16(af2, bf2v, acc2[i2][j2], 0, 0, 0);
          }
        }
      }
    }
    __syncthreads();
  }

  if (half == 0) {
    float s = topo_acc + __shfl_xor(topo_acc, 1);
    if ((tid & 1) == 0) {
      const int m = bm * 128 + (tid >> 1);
      a.out[(size_t)m * 69] = s + a.tb2[0];
    }
  } else {
#pragma unroll
    for (int i2 = 0; i2 < 2; ++i2)
#pragma unroll
      for (int j2 = 0; j2 < 4; ++j2)
#pragma unroll
        for (int r = 0; r < 4; ++r) {
          const int m = bm * 128 + wave * 32 + i2 * 16 + lq * 4 + r;
          const int o = j2 * 16 + lm;
          a.out[(size_t)m * 69 + 1 + o] = acc2[i2][j2][r] + a.ab2[o];
        }
  }
}

// ---------------- bond: layer1 GEMM (K=1664) with per-tile head partials --------
struct BDArgs {
  const float* gvec; const u16* cur; const float* znode; const float* src; const int* bidx;
  const u16* bt;     // BdT [512][1664] bf16
  const float* b1;   // bond_b1 [512] fp32
  const float* bw2;  // bond_w2 [512][4] fp32
  float* p4;         // [4][M][4] fp32 partials
};

__global__ __launch_bounds__(256) void gemm_bond(BDArgs a) {
  __shared__ u16 lds[8192];
  __shared__ u16 hbuf[128 * 136];
  const int tid = threadIdx.x;
  const int bm = blockIdx.x, t = blockIdx.y;
  const int wave = tid >> 6, lane = tid & 63;
  const int wm = wave >> 1, wn = wave & 1;
  const int lm = lane & 15, lq = lane >> 4;
  const int rA = tid >> 2, kq = (tid & 3) * 8;
  const int gm0 = bm * 128 + rA, gm1 = gm0 + 64;
  const int b0 = a.bidx[gm0], b1i = a.bidx[gm1];
  const int colbase = t * 128;

  u16* As = lds;
  u16* Bs = lds + 4096;
  u16* la0 = As + tid * 8;
  u16* la1 = As + 2048 + tid * 8;
  u16* lb0 = Bs + tid * 8;
  u16* lb1 = Bs + 2048 + tid * 8;

  f32x4 acc[4][4] = {};
  for (int kb = 0; kb < 1664; kb += 32) {
    *(short8*)lb0 = *(const short8*)(a.bt + (size_t)(colbase + rA) * 1664 + kb + kq);
    *(short8*)lb1 = *(const short8*)(a.bt + (size_t)(colbase + 64 + rA) * 1664 + kb + kq);
    if (kb >= 512 && kb < 1024) {
      const int krel = kb - 512 + kq;
      *(short8*)la0 = *(const short8*)(a.cur + (size_t)gm0 * 512 + krel);
      *(short8*)la1 = *(const short8*)(a.cur + (size_t)gm1 * 512 + krel);
    } else {
      const float* p; int ks, ld, r0 = gm0, r1 = gm1;
      if (kb < 512)       { p = a.gvec;  ks = 0;    ld = 512; }
      else if (kb < 1536) { p = a.znode; ks = 1024; ld = 512; }
      else                { p = a.src;   ks = 1536; ld = 128; r0 = b0; r1 = b1i; }
      const int krel = kb - ks + kq;
      *(short8*)la0 = ld8f(p + (size_t)r0 * ld + krel);
      *(short8*)la1 = ld8f(p + (size_t)r1 * ld + krel);
    }
    __syncthreads();
    short8 af[4], bfr[4];
#pragma unroll
    for (int i = 0; i < 4; ++i)
      af[i] = *(const short8*)&As[(wm * 64 + i * 16 + lm) * 32 + lq * 8];
#pragma unroll
    for (int j = 0; j < 4; ++j)
      bfr[j] = *(const short8*)&Bs[(wn * 64 + j * 16 + lm) * 32 + lq * 8];
#pragma unroll
    for (int i = 0; i < 4; ++i)
#pragma unroll
      for (int j = 0; j < 4; ++j)
        acc[i][j] = __builtin_amdgcn_mfma_f32_16x16x32_bf16(af[i], bfr[j], acc[i][j], 0, 0, 0);
    __syncthreads();
  }

  const int c0 = wn * 64 + lm;
  float bv[4];
#pragma unroll
  for (int j = 0; j < 4; ++j) bv[j] = a.b1[colbase + c0 + j * 16];
#pragma unroll
  for (int i = 0; i < 4; ++i) {
#pragma unroll
    for (int r = 0; r < 4; ++r) {
      const int rl = wm * 64 + i * 16 + lq * 4 + r;
#pragma unroll
      for (int j = 0; j < 4; ++j) {
        float v = acc[i][j][r] + bv[j];
        v = v > 0.f ? v : 0.f;
        hbuf[rl * 136 + c0 + j * 16] = f2bf(v);
      }
    }
  }
  __syncthreads();

  const int srow = tid >> 1, sh = tid & 1;
  const u16* hrow = &hbuf[srow * 136 + sh * 64];
  float s[4] = {0.f, 0.f, 0.f, 0.f};
  for (int cc = 0; cc < 64; ++cc) {
    const float h = bf2f(hrow[cc]);
#pragma unroll
    for (int o = 0; o < 4; ++o)
      s[o] += h * a.bw2[(colbase + sh * 64 + cc) * 4 + o];
  }
#pragma unroll
  for (int o = 0; o < 4; ++o) s[o] += __shfl_xor(s[o], 1);
  if ((tid & 1) == 0) {
    const int m = bm * 128 + srow;
#pragma unroll
    for (int o = 0; o < 4; ++o)
      a.p4[((size_t)t * M_ROWS + m) * 4 + o] = s[o];
  }
}

__global__ __launch_bounds__(256) void bond_fin(const float* p4, const float* bb2, float* out) {
  const int id = blockIdx.x * 256 + threadIdx.x;
  if (id >= M_ROWS * 4) return;
  const int m = id >> 2, o = id & 3;
  float v = bb2[o];
#pragma unroll
  for (int t = 0; t < 4; ++t) v += p4[((size_t)t * M_ROWS + m) * 4 + o];
  out[(size_t)m * 69 + 65 + o] = v;
}

// ---------------- weight transpose + fp32->bf16 conversion ----------------------
__global__ __launch_bounds__(256) void prep(
    const float* topo_w1, const float* atom_w1, const float* bond_w1,
    const float* rbond_w, const float* wbond_w, const float* atom_w2,
    u16* WbT, u16* RbT, u16* TAT, u16* BdT, u16* AT2) {
  int id = blockIdx.x * 256 + threadIdx.x;
  if (id < 512 * 512) { int n = id >> 9, k = id & 511; WbT[id] = f2bf(wbond_w[k * 512 + n]); return; }
  id -= 512 * 512;
  if (id < 512 * 576) { int n = id / 576, k = id % 576; RbT[id] = f2bf(rbond_w[k * 512 + n]); return; }
  id -= 512 * 576;
  if (id < 1024 * 1152) {
    int n = id / 1152, k = id % 1152;
    TAT[id] = f2bf((n < 512) ? topo_w1[k * 512 + n] : atom_w1[k * 512 + (n - 512)]);
    return;
  }
  id -= 1024 * 1152;
  if (id < 512 * 1664) { int n = id / 1664, k = id % 1664; BdT[id] = f2bf(bond_w1[k * 512 + n]); return; }
  id -= 512 * 1664;
  if (id < 64 * 512) { int n = id >> 9, k = id & 511; AT2[id] = f2bf(atom_w2[k * 64 + n]); return; }
}

extern "C" void kernel_launch(void* const* d_in, const int* in_sizes, int n_in,
                              void* d_out, int out_size, void* d_ws, size_t ws_size,
                              hipStream_t stream) {
  const float* src     = (const float*)d_in[0];
  const float* gvec    = (const float*)d_in[1];
  const float* xnode   = (const float*)d_in[2];
  const float* znode   = (const float*)d_in[3];
  const float* atom1h  = (const float*)d_in[4];
  const float* bond1h  = (const float*)d_in[5];
  const float* topo_w1 = (const float*)d_in[6];
  const float* topo_b1 = (const float*)d_in[7];
  const float* topo_w2 = (const float*)d_in[8];
  const float* topo_b2 = (const float*)d_in[9];
  const float* atom_w1 = (const float*)d_in[10];
  const float* atom_b1 = (const float*)d_in[11];
  const float* atom_w2 = (const float*)d_in[12];
  const float* atom_b2 = (const float*)d_in[13];
  const float* bond_w1 = (const float*)d_in[14];
  const float* bond_b1 = (const float*)d_in[15];
  const float* bond_w2 = (const float*)d_in[16];
  const float* bond_b2 = (const float*)d_in[17];
  const float* rbond_w = (const float*)d_in[18];
  const float* rbond_b = (const float*)d_in[19];
  const float* wbond_w = (const float*)d_in[20];
  const float* wbond_b = (const float*)d_in[21];
  const int* bidx      = (const int*)d_in[22];

  char* ws = (char*)d_ws;
  u16*  WbT  = (u16*)(ws + 0);         // 512x512 bf16
  u16*  RbT  = (u16*)(ws + 524288);    // 512x576
  u16*  TAT  = (u16*)(ws + 1114112);   // 1024x1152
  u16*  BdT  = (u16*)(ws + 3473408);   // 512x1664
  u16*  AT2  = (u16*)(ws + 5177344);   // 64x512
  float* P4  = (float*)(ws + 5244928); // 4 x M x 4 fp32
  u16*  hist = (u16*)(ws + 7342080);   // M x 512 bf16
  u16*  cur  = (u16*)(ws + 40896512);  // M x 512 bf16 (total ~71 MiB)

  prep<<<dim3(10240), dim3(256), 0, stream>>>(
      topo_w1, atom_w1, bond_w1, rbond_w, wbond_w, atom_w2,
      WbT, RbT, TAT, BdT, AT2);

  GArgs g1 = {};
  g1.seg[0] = {znode, 512, 0, 0}; g1.nseg = 1;
  g1.bt = WbT; g1.biasf = wbond_b; g1.out = hist; g1.K = 512; g1.N = 512;
  g1.tail_w = wbond_w + 512 * 512; g1.tail_x = bond1h;
  gemm_ms<<<dim3(256, 4), dim3(256), 0, stream>>>(g1);

  GArgs g2 = {};
  g2.seg[0] = {hist, 512, 0, 1}; g2.seg[1] = {atom1h, 64, 512, 0}; g2.nseg = 2;
  g2.bt = RbT; g2.biasf = rbond_b; g2.out = cur; g2.K = 576; g2.N = 512;
  gemm_ms<<<dim3(256, 4), dim3(256), 0, stream>>>(g2);

  TAArgs ta = {gvec, xnode, src, bidx, TAT, topo_b1, atom_b1,
               topo_w2, topo_b2, AT2, atom_b2, (float*)d_out};
  gemm_ta_heads<<<dim3(256, 2), dim3(256), 0, stream>>>(ta);

  BDArgs bd = {gvec, cur, znode, src, bidx, BdT, bond_b1, bond_w2, P4};
  gemm_bond<<<dim3(256, 4), dim3(256), 0, stream>>>(bd);

  bond_fin<<<dim3(512), dim3(256), 0, stream>>>(P4, bond_b2, (float*)d_out);
}